// Round 16
// baseline (407.697 us; speedup 1.0000x reference)
//
#include <hip/hip_runtime.h>
#include <math.h>

#define BB 2
#define NN 40960
#define KK 16

typedef float v2f __attribute__((ext_vector_type(2)));
typedef _Float16 h16;
typedef h16 h16x2 __attribute__((ext_vector_type(2)));

__device__ __forceinline__ v2f fma2(v2f a, v2f b, v2f c){
  return __builtin_elementwise_fma(a, b, c);
}
__device__ __forceinline__ v2f mk2(float a, float b){ v2f r; r.x=a; r.y=b; return r; }

#if __has_builtin(__builtin_amdgcn_fdot2)
__device__ __forceinline__ float dot2acc(h16x2 w, h16x2 f, float acc){
  return __builtin_amdgcn_fdot2(w, f, acc, false);
}
#else
__device__ __forceinline__ float dot2acc(h16x2 w, h16x2 f, float acc){
  return acc + (float)w.x*(float)f.x + (float)w.y*(float)f.y;
}
#endif
#if __has_builtin(__builtin_amdgcn_exp2f)
__device__ __forceinline__ float exp2fast(float x){ return __builtin_amdgcn_exp2f(x); }
#else
__device__ __forceinline__ float exp2fast(float x){ return __expf(x*0.6931471805599453f); }
#endif
#if __has_builtin(__builtin_amdgcn_cvt_pkrtz)
__device__ __forceinline__ h16x2 pkh(float a, float b){
  return __builtin_bit_cast(h16x2, __builtin_amdgcn_cvt_pkrtz(a,b));
}
#else
__device__ __forceinline__ h16x2 pkh(float a, float b){ h16x2 r; r.x=(h16)a; r.y=(h16)b; return r; }
#endif

// ---- 16-lane sum on the VALU pipe via DPP ----
template<int CTRL>
__device__ __forceinline__ float dppf(float x){
  return __int_as_float(__builtin_amdgcn_update_dpp(0, __float_as_int(x), CTRL, 0xF, 0xF, true));
}
__device__ __forceinline__ float red16_sum(float v){
  v += dppf<0xB1>(v);    // quad_perm:[1,0,3,2]  (xor 1)
  v += dppf<0x4E>(v);    // quad_perm:[2,3,0,1]  (xor 2)
  v += dppf<0x141>(v);   // row_half_mirror      (xor 4 equiv)
  v += dppf<0x140>(v);   // row_mirror           (xor 8 equiv)
  return v;
}
// intra-wave LDS producer->consumer fence (no cross-wave LDS sharing)
__device__ __forceinline__ void wave_sync(){
  asm volatile("s_waitcnt lgkmcnt(0)" ::: "memory");
  __builtin_amdgcn_sched_barrier(0);
}

// ---- pre-processed weights (f16 for dot2 paths, f32 elsewhere) ----
__device__ alignas(16) float g_pw1[32*10];
__device__ alignas(16) float g_pb1[32];
__device__ alignas(16) h16x2 g_w2h[32*16];   // mlp2 folded, f16 pairs
__device__ alignas(16) float g_pb2[32];
__device__ alignas(16) h16x2 g_fch1[64*32];  // fc1 * log2e, f16 pairs
__device__ alignas(16) float g_fcb1s[64];    // fc1 bias * log2e
__device__ alignas(16) h16x2 g_fch2[64*32];  // fc2 * log2e, f16 pairs
__device__ alignas(16) float g_fcb2s[64];
__device__ alignas(16) h16x2 g_cwh[32*32];   // ap1 mlp folded, f16 pairs (row-major)
__device__ alignas(16) float g_pcb[32];
__device__ alignas(16) h16x2 g_dwh[64*32];   // ap2 mlp folded, f16 pairs (row-major)
__device__ alignas(16) float g_pdb[64];

#define LOG2E 1.44269504088896f
#define AGP 68   // s_agg group pitch (floats): 272B -> groups start at banks 0/4/8/12

// Fused: feature transpose (blocks 0..319) + weight prep (last block)
__global__ __launch_bounds__(256) void k_pre(
  const float* __restrict__ feat, float* __restrict__ feat_t,
  const float* __restrict__ w1, const float* __restrict__ b1,
  const float* __restrict__ g1, const float* __restrict__ be1, const float* __restrict__ m1, const float* __restrict__ v1,
  const float* __restrict__ fc1w, const float* __restrict__ fc1b,
  const float* __restrict__ cw, const float* __restrict__ cb,
  const float* __restrict__ cg, const float* __restrict__ cbe, const float* __restrict__ cm, const float* __restrict__ cv,
  const float* __restrict__ w2, const float* __restrict__ b2,
  const float* __restrict__ g2, const float* __restrict__ be2, const float* __restrict__ m2, const float* __restrict__ v2,
  const float* __restrict__ fc2w, const float* __restrict__ fc2b,
  const float* __restrict__ dw, const float* __restrict__ db,
  const float* __restrict__ dg, const float* __restrict__ dbe, const float* __restrict__ dm, const float* __restrict__ dv)
{
  int tid = threadIdx.x;
  int bid = blockIdx.x;
  if (bid < BB*NN/256){
    int b = bid / (NN/256);
    int n = (bid % (NN/256))*256 + tid;
    float v[32];
    #pragma unroll
    for (int h=0; h<32; ++h) v[h] = feat[((size_t)(b*32+h))*NN + n];
    float* o = feat_t + ((size_t)b*NN + n)*32;
    #pragma unroll
    for (int h=0; h<32; h+=4){ *(float4*)(o+h) = make_float4(v[h],v[h+1],v[h+2],v[h+3]); }
    return;
  }
  for (int i=tid; i<320; i+=256){ int h=i/10;
    g_pw1[i] = w1[i] * (g1[h]*rsqrtf(v1[h]+1e-5f)); }
  if (tid<32){ float s=g1[tid]*rsqrtf(v1[tid]+1e-5f);
    g_pb1[tid] = (b1[tid]-m1[tid])*s+be1[tid]; }
  for (int i=tid; i<512; i+=256){ int h=i>>4, c=i&15;
    float s=g2[h]*rsqrtf(v2[h]+1e-5f);
    g_w2h[i] = pkh(w2[h*32+2*c]*s, w2[h*32+2*c+1]*s); }
  if (tid<32){ float s=g2[tid]*rsqrtf(v2[tid]+1e-5f);
    g_pb2[tid] = (b2[tid]-m2[tid])*s+be2[tid]; }
  for (int i=tid; i<2048; i+=256){ int o=i>>5, c=i&31;
    g_fch1[i] = pkh(fc1w[o*64+2*c]*LOG2E, fc1w[o*64+2*c+1]*LOG2E);
    g_fch2[i] = pkh(fc2w[o*64+2*c]*LOG2E, fc2w[o*64+2*c+1]*LOG2E); }
  if (tid<64){ g_fcb1s[tid] = fc1b[tid]*LOG2E; g_fcb2s[tid] = fc2b[tid]*LOG2E; }
  // ap1 folded -> f16 pairs (row-major: row h, 32 pairs)
  for (int i=tid; i<1024; i+=256){ int h=i>>5, c=i&31;
    float s=cg[h]*rsqrtf(cv[h]+1e-5f);
    g_cwh[i] = pkh(cw[h*64+2*c]*s, cw[h*64+2*c+1]*s); }
  if (tid<32){ float s=cg[tid]*rsqrtf(cv[tid]+1e-5f);
    g_pcb[tid] = (cb[tid]-cm[tid])*s+cbe[tid]; }
  // ap2 folded -> f16 pairs
  for (int i=tid; i<2048; i+=256){ int o=i>>5, c=i&31;
    float s=dg[o]*rsqrtf(dv[o]+1e-5f);
    g_dwh[i] = pkh(dw[o*64+2*c]*s, dw[o*64+2*c+1]*s); }
  if (tid<64){ float s=dg[tid]*rsqrtf(dv[tid]+1e-5f);
    g_pdb[tid] = (db[tid]-dm[tid])*s+dbe[tid]; }
}

__global__ __launch_bounds__(256,2) void k_stage1(
  const float* __restrict__ xyz, const float* __restrict__ feat_t, const int* __restrict__ nidx,
  float* __restrict__ fagg)
{
  __shared__ float s_agg[4][4][AGP];   // padded pitch: groups land on distinct banks
  int tid = threadIdx.x;
  int lane = tid & 63, wvv = tid >> 6;
  int k = lane & 15, ns = lane >> 4;
  int b = blockIdx.x / (NN/16);
  int n = (blockIdx.x % (NN/16))*16 + wvv*4 + ns;
  size_t bn = (size_t)b*NN + n;
  int idxv = nidx[bn*KK + k];

  // scattered gathers first; latency hides under mlp1 (f_nb -> f16, ch 0..31)
  h16x2 h2[32];
  {
    const float* fb = feat_t + ((size_t)b*NN + idxv)*32;
    #pragma unroll
    for (int h=0; h<32; h+=4){ float4 x=*(const float4*)(fb+h);
      h2[h>>1] = pkh(x.x,x.y); h2[(h>>1)+1] = pkh(x.z,x.w); }
  }
  const float* tp = xyz + bn*3;
  const float* qp = xyz + ((size_t)b*NN + idxv)*3;
  float t0=tp[0],t1=tp[1],t2=tp[2];
  float q0=qp[0],q1=qp[1],q2=qp[2];
  float r0=t0-q0,r1=t1-q1,r2=t2-q2;
  v2f e2[5] = { {sqrtf(r0*r0+r1*r1+r2*r2), r0}, {r1,r2}, {t0,t1}, {t2,q0}, {q1,q2} };

  // mlp1 (10->32, BN pre-folded, relu) — fp32 -> f16 pairs ch 32..63
  #pragma unroll
  for (int h=0; h<32; h+=2){
    const v2f* w0 = (const v2f*)(g_pw1 + h*10);
    const v2f* w1 = (const v2f*)(g_pw1 + (h+1)*10);
    v2f a0=mk2(g_pb1[h],0.f), a1=mk2(g_pb1[h+1],0.f);
    #pragma unroll
    for (int c=0; c<5; ++c){ a0=fma2(w0[c],e2[c],a0); a1=fma2(w1[c],e2[c],a1); }
    h2[16+(h>>1)] = pkh(fmaxf(a0.x+a0.y,0.f), fmaxf(a1.x+a1.y,0.f));
  }

  // fc1 (dot2, weights*log2e) + relu + exp2-softmax over K + agg — quads
  float sp4[4], sf4[4];
  #pragma unroll
  for (int ob=0; ob<64; ob+=4){
    const h16x2* w0 = &g_fch1[(ob+0)*32];
    const h16x2* w1p = &g_fch1[(ob+1)*32];
    const h16x2* w2p = &g_fch1[(ob+2)*32];
    const h16x2* w3p = &g_fch1[(ob+3)*32];
    float a0=g_fcb1s[ob+0], a1=g_fcb1s[ob+1], a2=g_fcb1s[ob+2], a3=g_fcb1s[ob+3];
    #pragma unroll
    for (int c=0; c<32; ++c){
      h16x2 f = h2[c];
      a0 = dot2acc(w0[c], f, a0); a1 = dot2acc(w1p[c], f, a1);
      a2 = dot2acc(w2p[c], f, a2); a3 = dot2acc(w3p[c], f, a3);
    }
    float p0=exp2fast(fmaxf(a0,0.f)), p1=exp2fast(fmaxf(a1,0.f));
    float p2=exp2fast(fmaxf(a2,0.f)), p3=exp2fast(fmaxf(a3,0.f));
    float f0=(float)h2[(ob>>1)+0].x, f1=(float)h2[(ob>>1)+0].y;
    float f2=(float)h2[(ob>>1)+1].x, f3=(float)h2[(ob>>1)+1].y;
    float q0v=f0*p0, q1v=f1*p1, q2v=f2*p2, q3v=f3*p3;
    float s0=red16_sum(p0), s1=red16_sum(p1), s2=red16_sum(p2), s3=red16_sum(p3);
    float t0v=red16_sum(q0v), t1v=red16_sum(q1v), t2v=red16_sum(q2v), t3v=red16_sum(q3v);
    if ((ob>>2)==k){
      sp4[0]=s0; sp4[1]=s1; sp4[2]=s2; sp4[3]=s3;
      sf4[0]=t0v; sf4[1]=t1v; sf4[2]=t2v; sf4[3]=t3v;
    }
  }
  float a0=__fdividef(sf4[0],sp4[0]), a1=__fdividef(sf4[1],sp4[1]);
  float a2=__fdividef(sf4[2],sp4[2]), a3=__fdividef(sf4[3],sp4[3]);

  // broadcast agg via per-wave LDS (lane k owns agg[4k..4k+3])
  *(float4*)&s_agg[wvv][ns][4*k] = make_float4(a0,a1,a2,a3);
  wave_sync();
  h16x2 hAg[32];
  {
    const float* ag = &s_agg[wvv][ns][0];
    #pragma unroll
    for (int c4=0;c4<16;++c4){ float4 x = *(const float4*)(ag + 4*c4);
      hAg[2*c4] = pkh(x.x,x.y); hAg[2*c4+1] = pkh(x.z,x.w); }
  }
  // ap1: lane k computes channels k and k+16 (lane-local dot2, no reductions)
  const h16x2* w0 = &g_cwh[k*32];
  const h16x2* w1 = &g_cwh[(k+16)*32];
  float o0 = g_pcb[k], o1 = g_pcb[k+16];
  #pragma unroll
  for (int c=0;c<32;++c){ o0 = dot2acc(w0[c], hAg[c], o0); o1 = dot2acc(w1[c], hAg[c], o1); }
  float* fo = fagg + bn*32;
  fo[k]    = fmaxf(o0, 0.f);
  fo[k+16] = fmaxf(o1, 0.f);
}

__global__ __launch_bounds__(256,2) void k_stage2(
  const float* __restrict__ xyz, const float* __restrict__ fagg, const int* __restrict__ nidx,
  float* __restrict__ outp)
{
  __shared__ float s_agg[4][4][AGP];
  int tid = threadIdx.x;
  int lane = tid & 63, wvv = tid >> 6;
  int k = lane & 15, ns = lane >> 4;
  int b = blockIdx.x / (NN/16);
  int n = (blockIdx.x % (NN/16))*16 + wvv*4 + ns;
  size_t bn = (size_t)b*NN + n;
  int idxv = nidx[bn*KK + k];

  // scattered gather first (fagg row -> f16, ch 0..31)
  h16x2 h2[32];
  {
    const float* fb = fagg + ((size_t)b*NN + idxv)*32;
    #pragma unroll
    for (int h=0; h<32; h+=4){ float4 x=*(const float4*)(fb+h);
      h2[h>>1] = pkh(x.x,x.y); h2[(h>>1)+1] = pkh(x.z,x.w); }
  }
  const float* tp = xyz + bn*3;
  const float* qp = xyz + ((size_t)b*NN + idxv)*3;
  float t0=tp[0],t1=tp[1],t2=tp[2];
  float q0=qp[0],q1=qp[1],q2=qp[2];
  float r0=t0-q0,r1=t1-q1,r2=t2-q2;
  v2f e2[5] = { {sqrtf(r0*r0+r1*r1+r2*r2), r0}, {r1,r2}, {t0,t1}, {t2,q0}, {q1,q2} };

  // recompute f_xyz (mlp1) — fp32 -> f16 pairs
  h16x2 hx[16];
  #pragma unroll
  for (int h=0; h<32; h+=2){
    const v2f* w0 = (const v2f*)(g_pw1 + h*10);
    const v2f* w1 = (const v2f*)(g_pw1 + (h+1)*10);
    v2f a0=mk2(g_pb1[h],0.f), a1=mk2(g_pb1[h+1],0.f);
    #pragma unroll
    for (int c=0; c<5; ++c){ a0=fma2(w0[c],e2[c],a0); a1=fma2(w1[c],e2[c],a1); }
    hx[h>>1] = pkh(fmaxf(a0.x+a0.y,0.f), fmaxf(a1.x+a1.y,0.f));
  }
  // mlp2 (32->32) via dot2 -> ch 32..63
  #pragma unroll
  for (int h=0; h<32; h+=2){
    const h16x2* wr0 = &g_w2h[(h+0)*16];
    const h16x2* wr1 = &g_w2h[(h+1)*16];
    float a0 = g_pb2[h+0], a1 = g_pb2[h+1];
    #pragma unroll
    for (int c=0; c<16; ++c){ h16x2 f=hx[c]; a0=dot2acc(wr0[c],f,a0); a1=dot2acc(wr1[c],f,a1); }
    h2[16+(h>>1)] = pkh(fmaxf(a0,0.f), fmaxf(a1,0.f));
  }

  // fc2 via dot2 + exp2-softmax + agg — quads
  float sp4[4], sf4[4];
  #pragma unroll
  for (int ob=0; ob<64; ob+=4){
    const h16x2* w0 = &g_fch2[(ob+0)*32];
    const h16x2* w1p = &g_fch2[(ob+1)*32];
    const h16x2* w2p = &g_fch2[(ob+2)*32];
    const h16x2* w3p = &g_fch2[(ob+3)*32];
    float a0=g_fcb2s[ob+0], a1=g_fcb2s[ob+1], a2=g_fcb2s[ob+2], a3=g_fcb2s[ob+3];
    #pragma unroll
    for (int c=0; c<32; ++c){
      h16x2 f = h2[c];
      a0 = dot2acc(w0[c], f, a0); a1 = dot2acc(w1p[c], f, a1);
      a2 = dot2acc(w2p[c], f, a2); a3 = dot2acc(w3p[c], f, a3);
    }
    float p0=exp2fast(fmaxf(a0,0.f)), p1=exp2fast(fmaxf(a1,0.f));
    float p2=exp2fast(fmaxf(a2,0.f)), p3=exp2fast(fmaxf(a3,0.f));
    float f0=(float)h2[(ob>>1)+0].x, f1=(float)h2[(ob>>1)+0].y;
    float f2=(float)h2[(ob>>1)+1].x, f3=(float)h2[(ob>>1)+1].y;
    float q0v=f0*p0, q1v=f1*p1, q2v=f2*p2, q3v=f3*p3;
    float s0=red16_sum(p0), s1=red16_sum(p1), s2=red16_sum(p2), s3=red16_sum(p3);
    float t0v=red16_sum(q0v), t1v=red16_sum(q1v), t2v=red16_sum(q2v), t3v=red16_sum(q3v);
    if ((ob>>2)==k){
      sp4[0]=s0; sp4[1]=s1; sp4[2]=s2; sp4[3]=s3;
      sf4[0]=t0v; sf4[1]=t1v; sf4[2]=t2v; sf4[3]=t3v;
    }
  }
  float a0=__fdividef(sf4[0],sp4[0]), a1=__fdividef(sf4[1],sp4[1]);
  float a2=__fdividef(sf4[2],sp4[2]), a3=__fdividef(sf4[3],sp4[3]);

  // broadcast agg via per-wave LDS
  *(float4*)&s_agg[wvv][ns][4*k] = make_float4(a0,a1,a2,a3);
  wave_sync();
  h16x2 hAg[32];
  {
    const float* ag = &s_agg[wvv][ns][0];
    #pragma unroll
    for (int c4=0;c4<16;++c4){ float4 x = *(const float4*)(ag + 4*c4);
      hAg[2*c4] = pkh(x.x,x.y); hAg[2*c4+1] = pkh(x.z,x.w); }
  }
  // ap2: lane k computes channels k+16j (lane-local dot2, no reductions)
  #pragma unroll
  for (int j=0; j<4; ++j){
    const h16x2* wr = &g_dwh[(k+16*j)*32];
    float acc = g_pdb[k+16*j];
    #pragma unroll
    for (int c=0;c<32;++c) acc = dot2acc(wr[c], hAg[c], acc);
    outp[((size_t)(b*64 + k + 16*j))*NN + n] = fmaxf(acc, 0.f);
  }
}

extern "C" void kernel_launch(void* const* d_in, const int* in_sizes, int n_in,
                              void* d_out, int out_size, void* d_ws, size_t ws_size,
                              hipStream_t stream){
  const float* xyz     = (const float*)d_in[0];
  const float* feature = (const float*)d_in[1];
  const int*   nidx    = (const int*)d_in[30];
  float* feat_t = (float*)d_ws;                       // (B,N,32)
  float* fagg   = feat_t + (size_t)BB*NN*32;          // (B,N,32)

  k_pre<<<BB*NN/256 + 1, 256, 0, stream>>>(feature, feat_t,
    (const float*)d_in[2],(const float*)d_in[3],(const float*)d_in[4],(const float*)d_in[5],
    (const float*)d_in[6],(const float*)d_in[7],
    (const float*)d_in[8],(const float*)d_in[9],
    (const float*)d_in[10],(const float*)d_in[11],(const float*)d_in[12],(const float*)d_in[13],
    (const float*)d_in[14],(const float*)d_in[15],
    (const float*)d_in[16],(const float*)d_in[17],(const float*)d_in[18],(const float*)d_in[19],
    (const float*)d_in[20],(const float*)d_in[21],
    (const float*)d_in[22],(const float*)d_in[23],
    (const float*)d_in[24],(const float*)d_in[25],(const float*)d_in[26],(const float*)d_in[27],
    (const float*)d_in[28],(const float*)d_in[29]);
  k_stage1<<<BB*NN/16, 256, 0, stream>>>(xyz, feat_t, nidx, fagg);
  k_stage2<<<BB*NN/16, 256, 0, stream>>>(xyz, fagg, nidx, (float*)d_out);
}

// Round 17
// 402.025 us; speedup vs baseline: 1.0141x; 1.0141x over previous
//
#include <hip/hip_runtime.h>
#include <math.h>

#define BB 2
#define NN 40960
#define KK 16

typedef float v2f __attribute__((ext_vector_type(2)));
typedef _Float16 h16;
typedef h16 h16x2 __attribute__((ext_vector_type(2)));
typedef unsigned int u32;

__device__ __forceinline__ v2f fma2(v2f a, v2f b, v2f c){
  return __builtin_elementwise_fma(a, b, c);
}
__device__ __forceinline__ v2f mk2(float a, float b){ v2f r; r.x=a; r.y=b; return r; }
__device__ __forceinline__ h16x2 bch(u32 u){ return __builtin_bit_cast(h16x2, u); }
__device__ __forceinline__ u32 bcu(h16x2 h){ return __builtin_bit_cast(u32, h); }

#if __has_builtin(__builtin_amdgcn_fdot2)
__device__ __forceinline__ float dot2acc(h16x2 w, h16x2 f, float acc){
  return __builtin_amdgcn_fdot2(w, f, acc, false);
}
#else
__device__ __forceinline__ float dot2acc(h16x2 w, h16x2 f, float acc){
  return acc + (float)w.x*(float)f.x + (float)w.y*(float)f.y;
}
#endif
#if __has_builtin(__builtin_amdgcn_exp2f)
__device__ __forceinline__ float exp2fast(float x){ return __builtin_amdgcn_exp2f(x); }
#else
__device__ __forceinline__ float exp2fast(float x){ return __expf(x*0.6931471805599453f); }
#endif
#if __has_builtin(__builtin_amdgcn_cvt_pkrtz)
__device__ __forceinline__ h16x2 pkh(float a, float b){
  return __builtin_bit_cast(h16x2, __builtin_amdgcn_cvt_pkrtz(a,b));
}
#else
__device__ __forceinline__ h16x2 pkh(float a, float b){ h16x2 r; r.x=(h16)a; r.y=(h16)b; return r; }
#endif

// ---- 16-lane sum on the VALU pipe via DPP ----
template<int CTRL>
__device__ __forceinline__ float dppf(float x){
  return __int_as_float(__builtin_amdgcn_update_dpp(0, __float_as_int(x), CTRL, 0xF, 0xF, true));
}
__device__ __forceinline__ float red16_sum(float v){
  v += dppf<0xB1>(v);    // quad_perm:[1,0,3,2]  (xor 1)
  v += dppf<0x4E>(v);    // quad_perm:[2,3,0,1]  (xor 2)
  v += dppf<0x141>(v);   // row_half_mirror      (xor 4 equiv)
  v += dppf<0x140>(v);   // row_mirror           (xor 8 equiv)
  return v;
}
// intra-wave LDS producer->consumer fence (no cross-wave LDS sharing)
__device__ __forceinline__ void wave_sync(){
  asm volatile("s_waitcnt lgkmcnt(0)" ::: "memory");
  __builtin_amdgcn_sched_barrier(0);
}

// ---- pre-processed weights (f16 for dot2 paths, f32 elsewhere) ----
__device__ alignas(16) float g_pw1[32*10];
__device__ alignas(16) float g_pb1[32];
__device__ alignas(16) h16x2 g_w2h[32*16];   // mlp2 folded, f16 pairs
__device__ alignas(16) float g_pb2[32];
__device__ alignas(16) h16x2 g_fch1[64*32];  // fc1 * log2e, f16 pairs
__device__ alignas(16) float g_fcb1s[64];    // fc1 bias * log2e
__device__ alignas(16) h16x2 g_fch2[64*32];  // fc2 * log2e, f16 pairs
__device__ alignas(16) float g_fcb2s[64];
__device__ alignas(16) h16x2 g_cwh[32*32];   // ap1 mlp folded, f16 pairs (row-major)
__device__ alignas(16) float g_pcb[32];
__device__ alignas(16) h16x2 g_dwh[64*32];   // ap2 mlp folded, f16 pairs (row-major)
__device__ alignas(16) float g_pdb[64];

#define LOG2E 1.44269504088896f
#define AGP 68   // s_agg group pitch (floats): 272B -> groups start at banks 0/4/8/12

// Fused: feature transpose->f16 (blocks 0..319) + weight prep (last block)
__global__ __launch_bounds__(256) void k_pre(
  const float* __restrict__ feat, h16x2* __restrict__ feat_t,
  const float* __restrict__ w1, const float* __restrict__ b1,
  const float* __restrict__ g1, const float* __restrict__ be1, const float* __restrict__ m1, const float* __restrict__ v1,
  const float* __restrict__ fc1w, const float* __restrict__ fc1b,
  const float* __restrict__ cw, const float* __restrict__ cb,
  const float* __restrict__ cg, const float* __restrict__ cbe, const float* __restrict__ cm, const float* __restrict__ cv,
  const float* __restrict__ w2, const float* __restrict__ b2,
  const float* __restrict__ g2, const float* __restrict__ be2, const float* __restrict__ m2, const float* __restrict__ v2,
  const float* __restrict__ fc2w, const float* __restrict__ fc2b,
  const float* __restrict__ dw, const float* __restrict__ db,
  const float* __restrict__ dg, const float* __restrict__ dbe, const float* __restrict__ dm, const float* __restrict__ dv)
{
  int tid = threadIdx.x;
  int bid = blockIdx.x;
  if (bid < BB*NN/256){
    int b = bid / (NN/256);
    int n = (bid % (NN/256))*256 + tid;
    float v[32];
    #pragma unroll
    for (int h=0; h<32; ++h) v[h] = feat[((size_t)(b*32+h))*NN + n];
    // store row as f16 pairs (64B) — same quantization point as the old consumer-side pkh
    u32 row[16];
    #pragma unroll
    for (int c=0; c<16; ++c) row[c] = bcu(pkh(v[2*c], v[2*c+1]));
    uint4* o = (uint4*)(feat_t + ((size_t)b*NN + n)*16);
    o[0] = make_uint4(row[0],row[1],row[2],row[3]);
    o[1] = make_uint4(row[4],row[5],row[6],row[7]);
    o[2] = make_uint4(row[8],row[9],row[10],row[11]);
    o[3] = make_uint4(row[12],row[13],row[14],row[15]);
    return;
  }
  for (int i=tid; i<320; i+=256){ int h=i/10;
    g_pw1[i] = w1[i] * (g1[h]*rsqrtf(v1[h]+1e-5f)); }
  if (tid<32){ float s=g1[tid]*rsqrtf(v1[tid]+1e-5f);
    g_pb1[tid] = (b1[tid]-m1[tid])*s+be1[tid]; }
  for (int i=tid; i<512; i+=256){ int h=i>>4, c=i&15;
    float s=g2[h]*rsqrtf(v2[h]+1e-5f);
    g_w2h[i] = pkh(w2[h*32+2*c]*s, w2[h*32+2*c+1]*s); }
  if (tid<32){ float s=g2[tid]*rsqrtf(v2[tid]+1e-5f);
    g_pb2[tid] = (b2[tid]-m2[tid])*s+be2[tid]; }
  for (int i=tid; i<2048; i+=256){ int o=i>>5, c=i&31;
    g_fch1[i] = pkh(fc1w[o*64+2*c]*LOG2E, fc1w[o*64+2*c+1]*LOG2E);
    g_fch2[i] = pkh(fc2w[o*64+2*c]*LOG2E, fc2w[o*64+2*c+1]*LOG2E); }
  if (tid<64){ g_fcb1s[tid] = fc1b[tid]*LOG2E; g_fcb2s[tid] = fc2b[tid]*LOG2E; }
  // ap1 folded -> f16 pairs (row-major: row h, 32 pairs)
  for (int i=tid; i<1024; i+=256){ int h=i>>5, c=i&31;
    float s=cg[h]*rsqrtf(cv[h]+1e-5f);
    g_cwh[i] = pkh(cw[h*64+2*c]*s, cw[h*64+2*c+1]*s); }
  if (tid<32){ float s=cg[tid]*rsqrtf(cv[tid]+1e-5f);
    g_pcb[tid] = (cb[tid]-cm[tid])*s+cbe[tid]; }
  // ap2 folded -> f16 pairs
  for (int i=tid; i<2048; i+=256){ int o=i>>5, c=i&31;
    float s=dg[o]*rsqrtf(dv[o]+1e-5f);
    g_dwh[i] = pkh(dw[o*64+2*c]*s, dw[o*64+2*c+1]*s); }
  if (tid<64){ float s=dg[tid]*rsqrtf(dv[tid]+1e-5f);
    g_pdb[tid] = (db[tid]-dm[tid])*s+dbe[tid]; }
}

__global__ __launch_bounds__(256,2) void k_stage1(
  const float* __restrict__ xyz, const h16x2* __restrict__ feat_t, const int* __restrict__ nidx,
  h16x2* __restrict__ fagg)
{
  __shared__ float s_agg[4][4][AGP];   // padded pitch: groups land on distinct banks
  int tid = threadIdx.x;
  int lane = tid & 63, wvv = tid >> 6;
  int k = lane & 15, ns = lane >> 4;
  int b = blockIdx.x / (NN/16);
  int n = (blockIdx.x % (NN/16))*16 + wvv*4 + ns;
  size_t bn = (size_t)b*NN + n;
  int idxv = nidx[bn*KK + k];

  // scattered gather first (f16 row, 64B); latency hides under mlp1
  h16x2 h2[32];
  {
    const uint4* fb = (const uint4*)(feat_t + ((size_t)b*NN + idxv)*16);
    uint4 q0=fb[0], q1=fb[1], q2=fb[2], q3=fb[3];
    h2[0]=bch(q0.x); h2[1]=bch(q0.y); h2[2]=bch(q0.z); h2[3]=bch(q0.w);
    h2[4]=bch(q1.x); h2[5]=bch(q1.y); h2[6]=bch(q1.z); h2[7]=bch(q1.w);
    h2[8]=bch(q2.x); h2[9]=bch(q2.y); h2[10]=bch(q2.z); h2[11]=bch(q2.w);
    h2[12]=bch(q3.x); h2[13]=bch(q3.y); h2[14]=bch(q3.z); h2[15]=bch(q3.w);
  }
  const float* tp = xyz + bn*3;
  const float* qp = xyz + ((size_t)b*NN + idxv)*3;
  float t0=tp[0],t1=tp[1],t2=tp[2];
  float q0=qp[0],q1=qp[1],q2=qp[2];
  float r0=t0-q0,r1=t1-q1,r2=t2-q2;
  v2f e2[5] = { {sqrtf(r0*r0+r1*r1+r2*r2), r0}, {r1,r2}, {t0,t1}, {t2,q0}, {q1,q2} };

  // mlp1 (10->32, BN pre-folded, relu) — fp32 -> f16 pairs ch 32..63
  #pragma unroll
  for (int h=0; h<32; h+=2){
    const v2f* w0 = (const v2f*)(g_pw1 + h*10);
    const v2f* w1 = (const v2f*)(g_pw1 + (h+1)*10);
    v2f a0=mk2(g_pb1[h],0.f), a1=mk2(g_pb1[h+1],0.f);
    #pragma unroll
    for (int c=0; c<5; ++c){ a0=fma2(w0[c],e2[c],a0); a1=fma2(w1[c],e2[c],a1); }
    h2[16+(h>>1)] = pkh(fmaxf(a0.x+a0.y,0.f), fmaxf(a1.x+a1.y,0.f));
  }

  // fc1 (dot2, weights*log2e) + relu + exp2-softmax over K + agg — quads
  float sp4[4], sf4[4];
  #pragma unroll
  for (int ob=0; ob<64; ob+=4){
    const h16x2* w0 = &g_fch1[(ob+0)*32];
    const h16x2* w1p = &g_fch1[(ob+1)*32];
    const h16x2* w2p = &g_fch1[(ob+2)*32];
    const h16x2* w3p = &g_fch1[(ob+3)*32];
    float a0=g_fcb1s[ob+0], a1=g_fcb1s[ob+1], a2=g_fcb1s[ob+2], a3=g_fcb1s[ob+3];
    #pragma unroll
    for (int c=0; c<32; ++c){
      h16x2 f = h2[c];
      a0 = dot2acc(w0[c], f, a0); a1 = dot2acc(w1p[c], f, a1);
      a2 = dot2acc(w2p[c], f, a2); a3 = dot2acc(w3p[c], f, a3);
    }
    float p0=exp2fast(fmaxf(a0,0.f)), p1=exp2fast(fmaxf(a1,0.f));
    float p2=exp2fast(fmaxf(a2,0.f)), p3=exp2fast(fmaxf(a3,0.f));
    float f0=(float)h2[(ob>>1)+0].x, f1=(float)h2[(ob>>1)+0].y;
    float f2=(float)h2[(ob>>1)+1].x, f3=(float)h2[(ob>>1)+1].y;
    float q0v=f0*p0, q1v=f1*p1, q2v=f2*p2, q3v=f3*p3;
    float s0=red16_sum(p0), s1=red16_sum(p1), s2=red16_sum(p2), s3=red16_sum(p3);
    float t0v=red16_sum(q0v), t1v=red16_sum(q1v), t2v=red16_sum(q2v), t3v=red16_sum(q3v);
    if ((ob>>2)==k){
      sp4[0]=s0; sp4[1]=s1; sp4[2]=s2; sp4[3]=s3;
      sf4[0]=t0v; sf4[1]=t1v; sf4[2]=t2v; sf4[3]=t3v;
    }
  }
  float a0=__fdividef(sf4[0],sp4[0]), a1=__fdividef(sf4[1],sp4[1]);
  float a2=__fdividef(sf4[2],sp4[2]), a3=__fdividef(sf4[3],sp4[3]);

  // broadcast agg via per-wave LDS (lane k owns agg[4k..4k+3])
  *(float4*)&s_agg[wvv][ns][4*k] = make_float4(a0,a1,a2,a3);
  wave_sync();
  h16x2 hAg[32];
  {
    const float* ag = &s_agg[wvv][ns][0];
    #pragma unroll
    for (int c4=0;c4<16;++c4){ float4 x = *(const float4*)(ag + 4*c4);
      hAg[2*c4] = pkh(x.x,x.y); hAg[2*c4+1] = pkh(x.z,x.w); }
  }
  // ap1: lane k computes channels 2k, 2k+1 (lane-local dot2) -> one h16x2 store
  const h16x2* w0 = &g_cwh[(2*k)*32];
  const h16x2* w1 = &g_cwh[(2*k+1)*32];
  float o0 = g_pcb[2*k], o1 = g_pcb[2*k+1];
  #pragma unroll
  for (int c=0;c<32;++c){ o0 = dot2acc(w0[c], hAg[c], o0); o1 = dot2acc(w1[c], hAg[c], o1); }
  fagg[bn*16 + k] = pkh(fmaxf(o0,0.f), fmaxf(o1,0.f));   // coalesced 64B/point row
}

__global__ __launch_bounds__(256,2) void k_stage2(
  const float* __restrict__ xyz, const h16x2* __restrict__ fagg, const int* __restrict__ nidx,
  float* __restrict__ outp)
{
  __shared__ float s_agg[4][4][AGP];
  int tid = threadIdx.x;
  int lane = tid & 63, wvv = tid >> 6;
  int k = lane & 15, ns = lane >> 4;
  int b = blockIdx.x / (NN/16);
  int n = (blockIdx.x % (NN/16))*16 + wvv*4 + ns;
  size_t bn = (size_t)b*NN + n;
  int idxv = nidx[bn*KK + k];

  // scattered gather first (fagg f16 row, 64B)
  h16x2 h2[32];
  {
    const uint4* fb = (const uint4*)(fagg + ((size_t)b*NN + idxv)*16);
    uint4 q0=fb[0], q1=fb[1], q2=fb[2], q3=fb[3];
    h2[0]=bch(q0.x); h2[1]=bch(q0.y); h2[2]=bch(q0.z); h2[3]=bch(q0.w);
    h2[4]=bch(q1.x); h2[5]=bch(q1.y); h2[6]=bch(q1.z); h2[7]=bch(q1.w);
    h2[8]=bch(q2.x); h2[9]=bch(q2.y); h2[10]=bch(q2.z); h2[11]=bch(q2.w);
    h2[12]=bch(q3.x); h2[13]=bch(q3.y); h2[14]=bch(q3.z); h2[15]=bch(q3.w);
  }
  const float* tp = xyz + bn*3;
  const float* qp = xyz + ((size_t)b*NN + idxv)*3;
  float t0=tp[0],t1=tp[1],t2=tp[2];
  float q0=qp[0],q1=qp[1],q2=qp[2];
  float r0=t0-q0,r1=t1-q1,r2=t2-q2;
  v2f e2[5] = { {sqrtf(r0*r0+r1*r1+r2*r2), r0}, {r1,r2}, {t0,t1}, {t2,q0}, {q1,q2} };

  // recompute f_xyz (mlp1) — fp32 -> f16 pairs
  h16x2 hx[16];
  #pragma unroll
  for (int h=0; h<32; h+=2){
    const v2f* w0 = (const v2f*)(g_pw1 + h*10);
    const v2f* w1 = (const v2f*)(g_pw1 + (h+1)*10);
    v2f a0=mk2(g_pb1[h],0.f), a1=mk2(g_pb1[h+1],0.f);
    #pragma unroll
    for (int c=0; c<5; ++c){ a0=fma2(w0[c],e2[c],a0); a1=fma2(w1[c],e2[c],a1); }
    hx[h>>1] = pkh(fmaxf(a0.x+a0.y,0.f), fmaxf(a1.x+a1.y,0.f));
  }
  // mlp2 (32->32) via dot2 -> ch 32..63
  #pragma unroll
  for (int h=0; h<32; h+=2){
    const h16x2* wr0 = &g_w2h[(h+0)*16];
    const h16x2* wr1 = &g_w2h[(h+1)*16];
    float a0 = g_pb2[h+0], a1 = g_pb2[h+1];
    #pragma unroll
    for (int c=0; c<16; ++c){ h16x2 f=hx[c]; a0=dot2acc(wr0[c],f,a0); a1=dot2acc(wr1[c],f,a1); }
    h2[16+(h>>1)] = pkh(fmaxf(a0,0.f), fmaxf(a1,0.f));
  }

  // fc2 via dot2 + exp2-softmax + agg — quads
  float sp4[4], sf4[4];
  #pragma unroll
  for (int ob=0; ob<64; ob+=4){
    const h16x2* w0 = &g_fch2[(ob+0)*32];
    const h16x2* w1p = &g_fch2[(ob+1)*32];
    const h16x2* w2p = &g_fch2[(ob+2)*32];
    const h16x2* w3p = &g_fch2[(ob+3)*32];
    float a0=g_fcb2s[ob+0], a1=g_fcb2s[ob+1], a2=g_fcb2s[ob+2], a3=g_fcb2s[ob+3];
    #pragma unroll
    for (int c=0; c<32; ++c){
      h16x2 f = h2[c];
      a0 = dot2acc(w0[c], f, a0); a1 = dot2acc(w1p[c], f, a1);
      a2 = dot2acc(w2p[c], f, a2); a3 = dot2acc(w3p[c], f, a3);
    }
    float p0=exp2fast(fmaxf(a0,0.f)), p1=exp2fast(fmaxf(a1,0.f));
    float p2=exp2fast(fmaxf(a2,0.f)), p3=exp2fast(fmaxf(a3,0.f));
    float f0=(float)h2[(ob>>1)+0].x, f1=(float)h2[(ob>>1)+0].y;
    float f2=(float)h2[(ob>>1)+1].x, f3=(float)h2[(ob>>1)+1].y;
    float q0v=f0*p0, q1v=f1*p1, q2v=f2*p2, q3v=f3*p3;
    float s0=red16_sum(p0), s1=red16_sum(p1), s2=red16_sum(p2), s3=red16_sum(p3);
    float t0v=red16_sum(q0v), t1v=red16_sum(q1v), t2v=red16_sum(q2v), t3v=red16_sum(q3v);
    if ((ob>>2)==k){
      sp4[0]=s0; sp4[1]=s1; sp4[2]=s2; sp4[3]=s3;
      sf4[0]=t0v; sf4[1]=t1v; sf4[2]=t2v; sf4[3]=t3v;
    }
  }
  float a0=__fdividef(sf4[0],sp4[0]), a1=__fdividef(sf4[1],sp4[1]);
  float a2=__fdividef(sf4[2],sp4[2]), a3=__fdividef(sf4[3],sp4[3]);

  // broadcast agg via per-wave LDS
  *(float4*)&s_agg[wvv][ns][4*k] = make_float4(a0,a1,a2,a3);
  wave_sync();
  h16x2 hAg[32];
  {
    const float* ag = &s_agg[wvv][ns][0];
    #pragma unroll
    for (int c4=0;c4<16;++c4){ float4 x = *(const float4*)(ag + 4*c4);
      hAg[2*c4] = pkh(x.x,x.y); hAg[2*c4+1] = pkh(x.z,x.w); }
  }
  // ap2: lane k computes channels k+16j (lane-local dot2, no reductions)
  #pragma unroll
  for (int j=0; j<4; ++j){
    const h16x2* wr = &g_dwh[(k+16*j)*32];
    float acc = g_pdb[k+16*j];
    #pragma unroll
    for (int c=0;c<32;++c) acc = dot2acc(wr[c], hAg[c], acc);
    outp[((size_t)(b*64 + k + 16*j))*NN + n] = fmaxf(acc, 0.f);
  }
}

extern "C" void kernel_launch(void* const* d_in, const int* in_sizes, int n_in,
                              void* d_out, int out_size, void* d_ws, size_t ws_size,
                              hipStream_t stream){
  const float* xyz     = (const float*)d_in[0];
  const float* feature = (const float*)d_in[1];
  const int*   nidx    = (const int*)d_in[30];
  h16x2* feat_t = (h16x2*)d_ws;                       // (B,N,16) f16 pairs
  h16x2* fagg   = feat_t + (size_t)BB*NN*16;          // (B,N,16) f16 pairs

  k_pre<<<BB*NN/256 + 1, 256, 0, stream>>>(feature, feat_t,
    (const float*)d_in[2],(const float*)d_in[3],(const float*)d_in[4],(const float*)d_in[5],
    (const float*)d_in[6],(const float*)d_in[7],
    (const float*)d_in[8],(const float*)d_in[9],
    (const float*)d_in[10],(const float*)d_in[11],(const float*)d_in[12],(const float*)d_in[13],
    (const float*)d_in[14],(const float*)d_in[15],
    (const float*)d_in[16],(const float*)d_in[17],(const float*)d_in[18],(const float*)d_in[19],
    (const float*)d_in[20],(const float*)d_in[21],
    (const float*)d_in[22],(const float*)d_in[23],
    (const float*)d_in[24],(const float*)d_in[25],(const float*)d_in[26],(const float*)d_in[27],
    (const float*)d_in[28],(const float*)d_in[29]);
  k_stage1<<<BB*NN/16, 256, 0, stream>>>(xyz, feat_t, nidx, fagg);
  k_stage2<<<BB*NN/16, 256, 0, stream>>>(xyz, fagg, nidx, (float*)d_out);
}